// Round 5
// baseline (20956.055 us; speedup 1.0000x reference)
//
#include <hip/hip_runtime.h>
#include <math.h>

#define B_ 64
#define T_ 2048
#define D_ 512
#define BT_ (B_ * T_)   // 131072
#define NGRP 4          // blocks per batch (channel quarters)
#define FSTRIDE 16      // flag padding (ints)
#define XCHG_HALF (NGRP * 64 * 128)   // 32768 floats per parity slot

typedef float f32x4 __attribute__((ext_vector_type(4)));

// ---------------------------------------------------------------------------
// Kernel 1: weight prep (transpose to k-major for coalesced GEMM/GEMV reads)
// ---------------------------------------------------------------------------
__global__ void prep_weights(const float* __restrict__ tau_w,
                             const float* __restrict__ mem_w,
                             float* __restrict__ Wcat,
                             float* __restrict__ WTh) {
    int idx = blockIdx.x * 256 + threadIdx.x;   // 0 .. 524287
    {
        int k = idx >> 10, j = idx & 1023;
        float v = (j < 512) ? tau_w[j * 1024 + k] : mem_w[(j - 512) * 512 + k];
        Wcat[idx] = v;
    }
    if (idx < 512 * 512) {
        int k = idx >> 9, d = idx & 511;
        WTh[idx] = tau_w[d * 1024 + 512 + k];
    }
}

// ---------------------------------------------------------------------------
// Kernel 2: f32 GEMM  C[131072][1024] = X[131072][512] @ Wcat[512][1024] + bias
// ---------------------------------------------------------------------------
__global__ __launch_bounds__(256, 2)
void gemm_xw(const float* __restrict__ X, const float* __restrict__ Wc,
             const float* __restrict__ tau_b, const float* __restrict__ mem_b,
             float* __restrict__ Aout, float* __restrict__ Mout) {
    __shared__ __align__(16) float As[16][128];  // [k][m]
    __shared__ __align__(16) float Bs[16][128];  // [k][n]
    const int bn = blockIdx.x;          // 0..7
    const int bm = blockIdx.y;          // 0..1023
    const int tid = threadIdx.x;
    const int tm = (tid >> 4) << 3;
    const int tn = (tid & 15) << 3;
    const int m0 = bm * 128, n0 = bn * 128;

    const float4* X4 = (const float4*)X;
    const float4* Wc4 = (const float4*)Wc;

    float acc[8][8];
#pragma unroll
    for (int i = 0; i < 8; i++)
#pragma unroll
        for (int j = 0; j < 8; j++) acc[i][j] = 0.0f;

    const int ar = tid >> 1;              // 0..127 row in tile
    const int ac2 = (tid & 1) * 2;        // float4 col 0 or 2
    const int bkr = tid >> 4;             // 0..15
    const int bc = (tid & 15) * 2;        // float4 col 0..30

    for (int kt = 0; kt < 512; kt += 16) {
        float4 av0 = X4[(m0 + ar) * 128 + (kt >> 2) + ac2];
        float4 av1 = X4[(m0 + ar) * 128 + (kt >> 2) + ac2 + 1];
        float4 bv0 = Wc4[(kt + bkr) * 256 + bn * 32 + bc];
        float4 bv1 = Wc4[(kt + bkr) * 256 + bn * 32 + bc + 1];
        __syncthreads();   // protect previous iteration's reads
        As[ac2 * 4 + 0][ar] = av0.x;
        As[ac2 * 4 + 1][ar] = av0.y;
        As[ac2 * 4 + 2][ar] = av0.z;
        As[ac2 * 4 + 3][ar] = av0.w;
        As[ac2 * 4 + 4][ar] = av1.x;
        As[ac2 * 4 + 5][ar] = av1.y;
        As[ac2 * 4 + 6][ar] = av1.z;
        As[ac2 * 4 + 7][ar] = av1.w;
        *(float4*)&Bs[bkr][bc * 4] = bv0;
        *(float4*)&Bs[bkr][bc * 4 + 4] = bv1;
        __syncthreads();
#pragma unroll
        for (int kk = 0; kk < 16; kk++) {
            float4 a0 = *(const float4*)&As[kk][tm];
            float4 a1 = *(const float4*)&As[kk][tm + 4];
            float4 b0 = *(const float4*)&Bs[kk][tn];
            float4 b1 = *(const float4*)&Bs[kk][tn + 4];
            float av[8] = {a0.x, a0.y, a0.z, a0.w, a1.x, a1.y, a1.z, a1.w};
            float bv[8] = {b0.x, b0.y, b0.z, b0.w, b1.x, b1.y, b1.z, b1.w};
#pragma unroll
            for (int i = 0; i < 8; i++)
#pragma unroll
                for (int j = 0; j < 8; j++)
                    acc[i][j] = fmaf(av[i], bv[j], acc[i][j]);
        }
    }

    const bool isA = (bn < 4);
    float* Cout = isA ? Aout : Mout;
    const float* bias = isA ? tau_b : mem_b;
    const int ncol0 = (isA ? n0 : n0 - 512) + tn;
    float bj[8];
#pragma unroll
    for (int j = 0; j < 8; j++) bj[j] = bias[ncol0 + j];
#pragma unroll
    for (int i = 0; i < 8; i++) {
        size_t off = (size_t)(m0 + tm + i) * 512 + ncol0;
        float4 o0, o1;
        o0.x = acc[i][0] + bj[0]; o0.y = acc[i][1] + bj[1];
        o0.z = acc[i][2] + bj[2]; o0.w = acc[i][3] + bj[3];
        o1.x = acc[i][4] + bj[4]; o1.y = acc[i][5] + bj[5];
        o1.z = acc[i][6] + bj[6]; o1.w = acc[i][7] + bj[7];
        *(float4*)&Cout[off] = o0;
        *(float4*)&Cout[off + 4] = o1;
    }
}

// ---------------------------------------------------------------------------
// Kernel 3: reset sync state (runs every launch -> graph-replay safe).
// ---------------------------------------------------------------------------
__global__ void init_sync(float* __restrict__ xchg, int* __restrict__ flags) {
    int idx = blockIdx.x * 256 + threadIdx.x;
    if (idx < XCHG_HALF) xchg[idx] = 1.0f;
    if (idx < 256 * FSTRIDE) flags[idx] = 0;
}

// ---------------------------------------------------------------------------
// Kernel 4: cooperative scan. 256 blocks = (batch bb, channel-quarter cq).
// Each block owns 128 output channels; the 512x128 weight slice lives in
// the AGPR file (32 f32x4 per thread, "+a" pins). Rounds 2-4 lesson: the
// v-class allocator spills ~190-live-reg loops no matter what
// (launch_bounds / waves_per_eu / "+v" pins all failed, VGPR stuck at
// 84-108 with per-step scratch/L2 reloads). AGPRs are an empty register
// class here (no MFMA in this kernel), so 128/256 a-regs is pressure-free;
// CDNA2+ VALU reads AGPR operands directly (or via cheap accvgpr_read).
// ---------------------------------------------------------------------------
__global__ __launch_bounds__(512)
__attribute__((amdgpu_waves_per_eu(2, 2)))
void scan_sync(const float* __restrict__ WTh,
               const float* __restrict__ Mm,
               const float* __restrict__ log_thresh,
               float* __restrict__ AmOut,   // A in / spikes out (d_out)
               float* __restrict__ OutTail, // d_out base for tau/v tails
               float* __restrict__ xchg,
               int* __restrict__ flags) {
    __shared__ __align__(16) float tau_s[512];
    __shared__ __align__(16) float part[8][128];

    const int blk = blockIdx.x;
    const int bb = blk & 63;     // batch
    const int cq = blk >> 6;     // channel quarter 0..3
    const int tid = threadIdx.x;

    const int kg = tid >> 6;     // k-eighth 0..7 (wave-uniform)
    const int dd6 = tid & 63;
    const int k0 = kg << 6;

    const int gj = tid >> 7;     // tau segment this thread gathers/waits on
    const int gd = tid & 127;

    const int de = cq * 128 + (tid & 127);   // epilogue channel (tid<128)

    // weight fragment: channels c0 = cq*128+dd6, c1 = c0+64; k in [k0,k0+64)
    f32x4 w0[16], w1[16];
    {
        const int c0 = cq * 128 + dd6;
        const int c1 = c0 + 64;
#pragma unroll
        for (int j = 0; j < 16; j++) {
            int k = k0 + 4 * j;
            w0[j].x = WTh[(k + 0) * 512 + c0];
            w0[j].y = WTh[(k + 1) * 512 + c0];
            w0[j].z = WTh[(k + 2) * 512 + c0];
            w0[j].w = WTh[(k + 3) * 512 + c0];
            w1[j].x = WTh[(k + 0) * 512 + c1];
            w1[j].y = WTh[(k + 1) * 512 + c1];
            w1[j].z = WTh[(k + 2) * 512 + c1];
            w1[j].w = WTh[(k + 3) * 512 + c1];
        }
    }
    // Park the fragment in the AGPR file before entering the loop.
    asm volatile("" : "+a"(w0[0]), "+a"(w0[1]), "+a"(w0[2]), "+a"(w0[3]),
                      "+a"(w0[4]), "+a"(w0[5]), "+a"(w0[6]), "+a"(w0[7]));
    asm volatile("" : "+a"(w0[8]), "+a"(w0[9]), "+a"(w0[10]), "+a"(w0[11]),
                      "+a"(w0[12]), "+a"(w0[13]), "+a"(w0[14]), "+a"(w0[15]));
    asm volatile("" : "+a"(w1[0]), "+a"(w1[1]), "+a"(w1[2]), "+a"(w1[3]),
                      "+a"(w1[4]), "+a"(w1[5]), "+a"(w1[6]), "+a"(w1[7]));
    asm volatile("" : "+a"(w1[8]), "+a"(w1[9]), "+a"(w1[10]), "+a"(w1[11]),
                      "+a"(w1[12]), "+a"(w1[13]), "+a"(w1[14]), "+a"(w1[15]));

    float thr = 0.f, v = 0.f, tau_new = 0.f;
    if (tid < 128) thr = 1.0f / (1.0f + expf(-log_thresh[de]));

    const f32x4* tau4 = (const f32x4*)tau_s;
    size_t abase = (size_t)bb * T_ * D_ + de;
    int* myflag = &flags[(bb * NGRP + cq) * FSTRIDE];
    const int* gflag = &flags[(bb * NGRP + gj) * FSTRIDE];
    const bool selfseg = (gj == cq);

    for (int c = 1; c <= T_; c++) {
        // AGPR pins inside the loop: liveness across the back-edge in the
        // a-class (remat/spill of the WTh loads is now pointless — the
        // a-file has zero other pressure).
        asm volatile("" : "+a"(w0[0]), "+a"(w0[1]), "+a"(w0[2]), "+a"(w0[3]),
                          "+a"(w0[4]), "+a"(w0[5]), "+a"(w0[6]), "+a"(w0[7]));
        asm volatile("" : "+a"(w0[8]), "+a"(w0[9]), "+a"(w0[10]), "+a"(w0[11]),
                          "+a"(w0[12]), "+a"(w0[13]), "+a"(w0[14]), "+a"(w0[15]));
        asm volatile("" : "+a"(w1[0]), "+a"(w1[1]), "+a"(w1[2]), "+a"(w1[3]),
                          "+a"(w1[4]), "+a"(w1[5]), "+a"(w1[6]), "+a"(w1[7]));
        asm volatile("" : "+a"(w1[8]), "+a"(w1[9]), "+a"(w1[10]), "+a"(w1[11]),
                          "+a"(w1[12]), "+a"(w1[13]), "+a"(w1[14]), "+a"(w1[15]));

        // early-issue this step's A and M (consumed after GEMV)
        float a_in = 0.f, m_in = 0.f;
        if (tid < 128) { a_in = AmOut[abase]; m_in = Mm[abase]; }

        // wait for segment gj to have published s_{c-1}
        if (!selfseg) {
            while (__hip_atomic_load(gflag, __ATOMIC_RELAXED,
                                     __HIP_MEMORY_SCOPE_AGENT) < c - 1) {}
        }
        asm volatile("" ::: "memory");   // no load motion above the spin
        tau_s[tid] = __hip_atomic_load(
            &xchg[(size_t)((c - 1) & 1) * XCHG_HALF + gj * 8192 + bb * 128 + gd],
            __ATOMIC_RELAXED, __HIP_MEMORY_SCOPE_AGENT);
        __syncthreads();

        float acc0 = 0.f, acc1 = 0.f;
#pragma unroll
        for (int j = 0; j < 16; j++) {
            f32x4 tv = tau4[kg * 16 + j];     // wave-uniform LDS broadcast
            acc0 = fmaf(tv.x, w0[j].x, acc0);
            acc0 = fmaf(tv.y, w0[j].y, acc0);
            acc0 = fmaf(tv.z, w0[j].z, acc0);
            acc0 = fmaf(tv.w, w0[j].w, acc0);
            acc1 = fmaf(tv.x, w1[j].x, acc1);
            acc1 = fmaf(tv.y, w1[j].y, acc1);
            acc1 = fmaf(tv.z, w1[j].z, acc1);
            acc1 = fmaf(tv.w, w1[j].w, acc1);
        }
        part[kg][dd6] = acc0;
        part[kg][64 + dd6] = acc1;
        __syncthreads();

        if (tid < 128) {
            const int dch = tid;
            float p = ((part[0][dch] + part[1][dch]) + (part[2][dch] + part[3][dch]))
                    + ((part[4][dch] + part[5][dch]) + (part[6][dch] + part[7][dch]));
            float pre = p + a_in;
            tau_new = 1.0f / (1.0f + expf(-pre));
            float alpha = expf(-1.0f / (tau_new + 1e-6f));
            v = alpha * v + (1.0f - alpha) * m_in;
            float s = (v >= thr) ? 1.0f : 0.0f;
            AmOut[abase] = s;           // overwrite A slot with spike
            v = v * (1.0f - s);
            __hip_atomic_store(
                &xchg[(size_t)(c & 1) * XCHG_HALF + cq * 8192 + bb * 128 + tid],
                tau_new, __ATOMIC_RELAXED, __HIP_MEMORY_SCOPE_AGENT);
            abase += D_;
        }
        __syncthreads();   // publish stores drained before flag
        if (tid == 0)
            __hip_atomic_store(myflag, c, __ATOMIC_RELEASE,
                               __HIP_MEMORY_SCOPE_AGENT);
    }

    if (tid < 128) {
        OutTail[(size_t)BT_ * D_ + (size_t)bb * D_ + de] = tau_new;
        OutTail[(size_t)BT_ * D_ + (size_t)B_ * D_ + (size_t)bb * D_ + de] = v;
    }
}

// ---------------------------------------------------------------------------
extern "C" void kernel_launch(void* const* d_in, const int* in_sizes, int n_in,
                              void* d_out, int out_size, void* d_ws, size_t ws_size,
                              hipStream_t stream) {
    (void)in_sizes; (void)n_in; (void)out_size; (void)ws_size;
    const float* x          = (const float*)d_in[0];
    const float* tau_w      = (const float*)d_in[1];
    const float* tau_b      = (const float*)d_in[2];
    const float* mem_w      = (const float*)d_in[3];
    const float* mem_b      = (const float*)d_in[4];
    const float* log_thresh = (const float*)d_in[5];
    float* out = (float*)d_out;

    // workspace layout
    float* Wcat = (float*)d_ws;            // 512*1024 (dead after GEMM)
    float* WTh  = Wcat + 512 * 1024;       // 512*512
    float* Mout = WTh + 512 * 512;         // 131072*512
    // sync state reuses the Wcat region (GEMM is done before init_sync runs)
    float* xchg  = Wcat;                              // 2*XCHG_HALF floats
    int*   flags = (int*)(Wcat + 2 * XCHG_HALF);      // 256*FSTRIDE ints

    float* Aout = out;                     // spikes region doubles as A buffer

    prep_weights<<<2048, 256, 0, stream>>>(tau_w, mem_w, Wcat, WTh);
    gemm_xw<<<dim3(8, 1024), 256, 0, stream>>>(x, Wcat, tau_b, mem_b, Aout, Mout);
    init_sync<<<128, 256, 0, stream>>>(xchg, flags);

    const float* WThc = WTh;
    const float* Mmc  = Mout;
    const float* ltc  = log_thresh;
    float* outp = out;
    float* xchgp = xchg;
    int* flagsp = flags;
    void* args[7] = {(void*)&WThc, (void*)&Mmc, (void*)&ltc,
                     (void*)&Aout, (void*)&outp, (void*)&xchgp, (void*)&flagsp};
    hipLaunchCooperativeKernel((const void*)scan_sync, dim3(256), dim3(512),
                               args, 0, stream);
}

// Round 6
// 14858.754 us; speedup vs baseline: 1.4104x; 1.4104x over previous
//
#include <hip/hip_runtime.h>
#include <math.h>

#define B_ 64
#define T_ 2048
#define D_ 512
#define BT_ (B_ * T_)   // 131072
#define FSTRIDE 16      // flag padding (ints)
#define XCHG_HALF (B_ * D_)   // 32768 floats per parity slot: [batch][512]

// ---------------------------------------------------------------------------
// Kernel 1: weight prep (transpose to k-major for coalesced GEMM/GEMV reads)
//   Wcat[k][j], j<512:  tau_w[j*1024 + k]      (x -> gate half)
//              j>=512:  mem_w[(j-512)*512 + k] (x -> mem)
//   WTh[k][d]        :  tau_w[d*1024 + 512+k]  (tau -> gate recurrent half)
// ---------------------------------------------------------------------------
__global__ void prep_weights(const float* __restrict__ tau_w,
                             const float* __restrict__ mem_w,
                             float* __restrict__ Wcat,
                             float* __restrict__ WTh) {
    int idx = blockIdx.x * 256 + threadIdx.x;   // 0 .. 524287
    {
        int k = idx >> 10, j = idx & 1023;
        float v = (j < 512) ? tau_w[j * 1024 + k] : mem_w[(j - 512) * 512 + k];
        Wcat[idx] = v;
    }
    if (idx < 512 * 512) {
        int k = idx >> 9, d = idx & 511;
        WTh[idx] = tau_w[d * 1024 + 512 + k];
    }
}

// ---------------------------------------------------------------------------
// Kernel 2: f32 GEMM  C[131072][1024] = X[131072][512] @ Wcat[512][1024] + bias
// ---------------------------------------------------------------------------
__global__ __launch_bounds__(256, 2)
void gemm_xw(const float* __restrict__ X, const float* __restrict__ Wc,
             const float* __restrict__ tau_b, const float* __restrict__ mem_b,
             float* __restrict__ Aout, float* __restrict__ Mout) {
    __shared__ __align__(16) float As[16][128];  // [k][m]
    __shared__ __align__(16) float Bs[16][128];  // [k][n]
    const int bn = blockIdx.x;          // 0..7
    const int bm = blockIdx.y;          // 0..1023
    const int tid = threadIdx.x;
    const int tm = (tid >> 4) << 3;
    const int tn = (tid & 15) << 3;
    const int m0 = bm * 128, n0 = bn * 128;

    const float4* X4 = (const float4*)X;
    const float4* Wc4 = (const float4*)Wc;

    float acc[8][8];
#pragma unroll
    for (int i = 0; i < 8; i++)
#pragma unroll
        for (int j = 0; j < 8; j++) acc[i][j] = 0.0f;

    const int ar = tid >> 1;              // 0..127 row in tile
    const int ac2 = (tid & 1) * 2;        // float4 col 0 or 2
    const int bkr = tid >> 4;             // 0..15
    const int bc = (tid & 15) * 2;        // float4 col 0..30

    for (int kt = 0; kt < 512; kt += 16) {
        float4 av0 = X4[(m0 + ar) * 128 + (kt >> 2) + ac2];
        float4 av1 = X4[(m0 + ar) * 128 + (kt >> 2) + ac2 + 1];
        float4 bv0 = Wc4[(kt + bkr) * 256 + bn * 32 + bc];
        float4 bv1 = Wc4[(kt + bkr) * 256 + bn * 32 + bc + 1];
        __syncthreads();   // protect previous iteration's reads
        As[ac2 * 4 + 0][ar] = av0.x;
        As[ac2 * 4 + 1][ar] = av0.y;
        As[ac2 * 4 + 2][ar] = av0.z;
        As[ac2 * 4 + 3][ar] = av0.w;
        As[ac2 * 4 + 4][ar] = av1.x;
        As[ac2 * 4 + 5][ar] = av1.y;
        As[ac2 * 4 + 6][ar] = av1.z;
        As[ac2 * 4 + 7][ar] = av1.w;
        *(float4*)&Bs[bkr][bc * 4] = bv0;
        *(float4*)&Bs[bkr][bc * 4 + 4] = bv1;
        __syncthreads();
#pragma unroll
        for (int kk = 0; kk < 16; kk++) {
            float4 a0 = *(const float4*)&As[kk][tm];
            float4 a1 = *(const float4*)&As[kk][tm + 4];
            float4 b0 = *(const float4*)&Bs[kk][tn];
            float4 b1 = *(const float4*)&Bs[kk][tn + 4];
            float av[8] = {a0.x, a0.y, a0.z, a0.w, a1.x, a1.y, a1.z, a1.w};
            float bv[8] = {b0.x, b0.y, b0.z, b0.w, b1.x, b1.y, b1.z, b1.w};
#pragma unroll
            for (int i = 0; i < 8; i++)
#pragma unroll
                for (int j = 0; j < 8; j++)
                    acc[i][j] = fmaf(av[i], bv[j], acc[i][j]);
        }
    }

    const bool isA = (bn < 4);
    float* Cout = isA ? Aout : Mout;
    const float* bias = isA ? tau_b : mem_b;
    const int ncol0 = (isA ? n0 : n0 - 512) + tn;
    float bj[8];
#pragma unroll
    for (int j = 0; j < 8; j++) bj[j] = bias[ncol0 + j];
#pragma unroll
    for (int i = 0; i < 8; i++) {
        size_t off = (size_t)(m0 + tm + i) * 512 + ncol0;
        float4 o0, o1;
        o0.x = acc[i][0] + bj[0]; o0.y = acc[i][1] + bj[1];
        o0.z = acc[i][2] + bj[2]; o0.w = acc[i][3] + bj[3];
        o1.x = acc[i][4] + bj[4]; o1.y = acc[i][5] + bj[5];
        o1.z = acc[i][6] + bj[6]; o1.w = acc[i][7] + bj[7];
        *(float4*)&Cout[off] = o0;
        *(float4*)&Cout[off + 4] = o1;
    }
}

// ---------------------------------------------------------------------------
// Kernel 3: reset sync state (runs every launch -> graph-replay safe).
// Slot-0 of xchg holds s_0 = initial tau = ones; flags = 0.
// ---------------------------------------------------------------------------
__global__ void init_sync(float* __restrict__ xchg, int* __restrict__ flags) {
    int idx = blockIdx.x * 256 + threadIdx.x;
    if (idx < XCHG_HALF) xchg[idx] = 1.0f;
    if (idx < 256 * FSTRIDE) flags[idx] = 0;
}

// ---------------------------------------------------------------------------
// Kernel 4: cooperative scan, LDS-resident weights (rounds 2-5 lesson: the
// register allocator spills any ~128-float/thread resident array — "+v",
// waves_per_eu, "+a" pins all failed; LDS cannot be spilled).
//
// 256 blocks = (seg sg in [0,8) of 64 channels) x (batch-pair bp in [0,32)).
// Block stages its 512x64 weight slice (128 KB) into LDS once, then serves
// TWO batches per step (each weight read once, used twice -> halves LDS BW
// per FMA). Partner blocks of a pair {sg'*32+bp} all map to XCD bp%8 ->
// flags/xchg stay in one XCD's L2.
//
// LDS layout: w_lds f4(kq,ch) = {W[4kq..4kq+3][sg*64+ch]} -> GEMV reads are
// lane-consecutive b128 (conflict-free); tau reads are half-wave broadcasts;
// part[b][ks][ch] gives bank = ch%32 -> 2 lanes/bank (free) on write+reduce.
// ---------------------------------------------------------------------------
__global__ __launch_bounds__(512)
__attribute__((amdgpu_waves_per_eu(2, 2)))
void scan_lds(const float* __restrict__ WTh,
              const float* __restrict__ Mm,
              const float* __restrict__ log_thresh,
              float* __restrict__ AmOut,   // A in / spikes out (d_out)
              float* __restrict__ OutTail, // d_out base for tau/v tails
              float* __restrict__ xchg,
              int* __restrict__ flags) {
    __shared__ __align__(16) float4 w_lds[8192];       // 128 KB
    __shared__ __align__(16) float tau_s[2][512];      // 4 KB
    __shared__ __align__(16) float part[2][16][64];    // 8 KB

    const int blk = blockIdx.x;
    const int sg = blk >> 5;     // channel segment 0..7 (64 channels)
    const int bp = blk & 31;     // batch pair 0..31
    const int tid = threadIdx.x;

    // ---- stage weight slice into LDS (one-time, 128 KB) ----
    {
        const int ch = tid & 63;
        const int kr8 = tid >> 6;          // 0..7
        float* wl = (float*)w_lds;
        for (int i = 0; i < 64; i++) {
            int krow = i * 8 + kr8;
            float val = WTh[krow * 512 + sg * 64 + ch];
            wl[(krow >> 2) * 256 + ch * 4 + (krow & 3)] = val;
        }
    }

    // epilogue identity (tid < 128): batch-in-pair b, channel ch
    const int eb = tid >> 6;             // 0 or 1 (for tid<128)
    const int ech = tid & 63;
    const int gch = sg * 64 + ech;       // global channel
    float thr = 0.f, v = 0.f, tau_keep = 0.f;
    if (tid < 128) thr = 1.0f / (1.0f + expf(-log_thresh[gch]));
    size_t abase = ((size_t)(bp * 2 + eb) * T_) * D_ + gch;

    // GEMV identity
    const int cp = tid & 31;             // channel pair (cp, cp+32)
    const int ks = tid >> 5;             // k-slice 0..15 (window of 32 k)

    // gather identity (tid < 256): batch-in-pair gb, f4 element ge
    const int gb = (tid >> 7) & 1;
    const int ge = tid & 127;
    const int gseg = ge >> 4;            // which segment this f4 belongs to
    const int* gflag = &flags[(gseg * 32 + bp) * FSTRIDE];
    int* myflag = &flags[blk * FSTRIDE];

    __syncthreads();   // weights staged

    for (int c = 1; c <= T_; c++) {
        // prefetch this step's A and M (consumed in epilogue, 3 barriers later)
        float a_in = 0.f, m_in = 0.f;
        if (tid < 128) { a_in = AmOut[abase]; m_in = Mm[abase]; }

        // ---- gather tau (per-segment spin, then 4 agent-scope loads) ----
        if (tid < 256) {
            if (gseg != sg) {
                while (__hip_atomic_load(gflag, __ATOMIC_RELAXED,
                                         __HIP_MEMORY_SCOPE_AGENT) < c - 1) {}
            }
            asm volatile("" ::: "memory");
            const float* src = &xchg[(size_t)((c - 1) & 1) * XCHG_HALF
                                     + (bp * 2 + gb) * 512 + ge * 4];
            float x0 = __hip_atomic_load(src + 0, __ATOMIC_RELAXED,
                                         __HIP_MEMORY_SCOPE_AGENT);
            float x1 = __hip_atomic_load(src + 1, __ATOMIC_RELAXED,
                                         __HIP_MEMORY_SCOPE_AGENT);
            float x2 = __hip_atomic_load(src + 2, __ATOMIC_RELAXED,
                                         __HIP_MEMORY_SCOPE_AGENT);
            float x3 = __hip_atomic_load(src + 3, __ATOMIC_RELAXED,
                                         __HIP_MEMORY_SCOPE_AGENT);
            *(float4*)&tau_s[gb][ge * 4] = make_float4(x0, x1, x2, x3);
        }
        __syncthreads();   // B: tau_s ready

        // ---- GEMV: 2 channels x 2 batches over k-window [ks*32, ks*32+32) ----
        float acc00 = 0.f, acc01 = 0.f, acc10 = 0.f, acc11 = 0.f;
#pragma unroll
        for (int q = 0; q < 8; q++) {
            const int qq = ks * 8 + q;
            float4 wA = w_lds[qq * 64 + cp];
            float4 wB = w_lds[qq * 64 + cp + 32];
            float4 t0 = *(const float4*)&tau_s[0][qq * 4];
            float4 t1 = *(const float4*)&tau_s[1][qq * 4];
            acc00 = fmaf(t0.x, wA.x, acc00); acc00 = fmaf(t0.y, wA.y, acc00);
            acc00 = fmaf(t0.z, wA.z, acc00); acc00 = fmaf(t0.w, wA.w, acc00);
            acc01 = fmaf(t0.x, wB.x, acc01); acc01 = fmaf(t0.y, wB.y, acc01);
            acc01 = fmaf(t0.z, wB.z, acc01); acc01 = fmaf(t0.w, wB.w, acc01);
            acc10 = fmaf(t1.x, wA.x, acc10); acc10 = fmaf(t1.y, wA.y, acc10);
            acc10 = fmaf(t1.z, wA.z, acc10); acc10 = fmaf(t1.w, wA.w, acc10);
            acc11 = fmaf(t1.x, wB.x, acc11); acc11 = fmaf(t1.y, wB.y, acc11);
            acc11 = fmaf(t1.z, wB.z, acc11); acc11 = fmaf(t1.w, wB.w, acc11);
        }
        part[0][ks][cp]      = acc00;
        part[0][ks][cp + 32] = acc01;
        part[1][ks][cp]      = acc10;
        part[1][ks][cp + 32] = acc11;
        __syncthreads();   // C: partials ready

        // ---- epilogue on 128 threads ----
        if (tid < 128) {
            float sum = 0.f;
#pragma unroll
            for (int j = 0; j < 16; j++) sum += part[eb][j][ech];
            float pre = sum + a_in;
            float tau = 1.0f / (1.0f + expf(-pre));
            float alpha = expf(-1.0f / (tau + 1e-6f));
            v = alpha * v + (1.0f - alpha) * m_in;
            float s = (v >= thr) ? 1.0f : 0.0f;
            AmOut[abase] = s;            // overwrite A slot with spike
            v = v * (1.0f - s);
            tau_keep = tau;
            __hip_atomic_store(&xchg[(size_t)(c & 1) * XCHG_HALF
                                     + (bp * 2 + eb) * 512 + gch],
                               tau, __ATOMIC_RELAXED, __HIP_MEMORY_SCOPE_AGENT);
            abase += D_;
        }
        __syncthreads();   // D: publish stores drained (vmcnt) before flag
        if (tid == 0)
            __hip_atomic_store(myflag, c, __ATOMIC_RELEASE,
                               __HIP_MEMORY_SCOPE_AGENT);
    }

    if (tid < 128) {
        const size_t batch = bp * 2 + eb;
        OutTail[(size_t)BT_ * D_ + batch * D_ + gch] = tau_keep;
        OutTail[(size_t)BT_ * D_ + (size_t)B_ * D_ + batch * D_ + gch] = v;
    }
}

// ---------------------------------------------------------------------------
extern "C" void kernel_launch(void* const* d_in, const int* in_sizes, int n_in,
                              void* d_out, int out_size, void* d_ws, size_t ws_size,
                              hipStream_t stream) {
    (void)in_sizes; (void)n_in; (void)out_size; (void)ws_size;
    const float* x          = (const float*)d_in[0];
    const float* tau_w      = (const float*)d_in[1];
    const float* tau_b      = (const float*)d_in[2];
    const float* mem_w      = (const float*)d_in[3];
    const float* mem_b      = (const float*)d_in[4];
    const float* log_thresh = (const float*)d_in[5];
    float* out = (float*)d_out;

    // workspace layout
    float* Wcat = (float*)d_ws;            // 512*1024 (dead after GEMM)
    float* WTh  = Wcat + 512 * 1024;       // 512*512
    float* Mout = WTh + 512 * 512;         // 131072*512
    // sync state reuses the Wcat region (GEMM is done before init_sync runs)
    float* xchg  = Wcat;                              // 2*XCHG_HALF floats
    int*   flags = (int*)(Wcat + 2 * XCHG_HALF);      // 256*FSTRIDE ints

    float* Aout = out;                     // spikes region doubles as A buffer

    prep_weights<<<2048, 256, 0, stream>>>(tau_w, mem_w, Wcat, WTh);
    gemm_xw<<<dim3(8, 1024), 256, 0, stream>>>(x, Wcat, tau_b, mem_b, Aout, Mout);
    init_sync<<<128, 256, 0, stream>>>(xchg, flags);

    const float* WThc = WTh;
    const float* Mmc  = Mout;
    const float* ltc  = log_thresh;
    float* outp = out;
    float* xchgp = xchg;
    int* flagsp = flags;
    void* args[7] = {(void*)&WThc, (void*)&Mmc, (void*)&ltc,
                     (void*)&Aout, (void*)&outp, (void*)&xchgp, (void*)&flagsp};
    hipLaunchCooperativeKernel((const void*)scan_lds, dim3(256), dim3(512),
                               args, 0, stream);
}

// Round 7
// 6441.596 us; speedup vs baseline: 3.2532x; 2.3067x over previous
//
#include <hip/hip_runtime.h>
#include <math.h>

#define B_ 64
#define T_ 2048
#define D_ 512
#define BT_ (B_ * T_)   // 131072
#define XWORDS (B_ * D_)   // 32768 8-byte words per parity slot: [batch][512]

typedef unsigned long long u64;

// ---------------------------------------------------------------------------
// Kernel 1: weight prep (transpose to k-major for coalesced GEMM/GEMV reads)
// ---------------------------------------------------------------------------
__global__ void prep_weights(const float* __restrict__ tau_w,
                             const float* __restrict__ mem_w,
                             float* __restrict__ Wcat,
                             float* __restrict__ WTh) {
    int idx = blockIdx.x * 256 + threadIdx.x;   // 0 .. 524287
    {
        int k = idx >> 10, j = idx & 1023;
        float v = (j < 512) ? tau_w[j * 1024 + k] : mem_w[(j - 512) * 512 + k];
        Wcat[idx] = v;
    }
    if (idx < 512 * 512) {
        int k = idx >> 9, d = idx & 511;
        WTh[idx] = tau_w[d * 1024 + 512 + k];
    }
}

// ---------------------------------------------------------------------------
// Kernel 2: f32 GEMM  C[131072][1024] = X[131072][512] @ Wcat[512][1024] + bias
// ---------------------------------------------------------------------------
__global__ __launch_bounds__(256, 2)
void gemm_xw(const float* __restrict__ X, const float* __restrict__ Wc,
             const float* __restrict__ tau_b, const float* __restrict__ mem_b,
             float* __restrict__ Aout, float* __restrict__ Mout) {
    __shared__ __align__(16) float As[16][128];  // [k][m]
    __shared__ __align__(16) float Bs[16][128];  // [k][n]
    const int bn = blockIdx.x;          // 0..7
    const int bm = blockIdx.y;          // 0..1023
    const int tid = threadIdx.x;
    const int tm = (tid >> 4) << 3;
    const int tn = (tid & 15) << 3;
    const int m0 = bm * 128, n0 = bn * 128;

    const float4* X4 = (const float4*)X;
    const float4* Wc4 = (const float4*)Wc;

    float acc[8][8];
#pragma unroll
    for (int i = 0; i < 8; i++)
#pragma unroll
        for (int j = 0; j < 8; j++) acc[i][j] = 0.0f;

    const int ar = tid >> 1;              // 0..127 row in tile
    const int ac2 = (tid & 1) * 2;        // float4 col 0 or 2
    const int bkr = tid >> 4;             // 0..15
    const int bc = (tid & 15) * 2;        // float4 col 0..30

    for (int kt = 0; kt < 512; kt += 16) {
        float4 av0 = X4[(m0 + ar) * 128 + (kt >> 2) + ac2];
        float4 av1 = X4[(m0 + ar) * 128 + (kt >> 2) + ac2 + 1];
        float4 bv0 = Wc4[(kt + bkr) * 256 + bn * 32 + bc];
        float4 bv1 = Wc4[(kt + bkr) * 256 + bn * 32 + bc + 1];
        __syncthreads();   // protect previous iteration's reads
        As[ac2 * 4 + 0][ar] = av0.x;
        As[ac2 * 4 + 1][ar] = av0.y;
        As[ac2 * 4 + 2][ar] = av0.z;
        As[ac2 * 4 + 3][ar] = av0.w;
        As[ac2 * 4 + 4][ar] = av1.x;
        As[ac2 * 4 + 5][ar] = av1.y;
        As[ac2 * 4 + 6][ar] = av1.z;
        As[ac2 * 4 + 7][ar] = av1.w;
        *(float4*)&Bs[bkr][bc * 4] = bv0;
        *(float4*)&Bs[bkr][bc * 4 + 4] = bv1;
        __syncthreads();
#pragma unroll
        for (int kk = 0; kk < 16; kk++) {
            float4 a0 = *(const float4*)&As[kk][tm];
            float4 a1 = *(const float4*)&As[kk][tm + 4];
            float4 b0 = *(const float4*)&Bs[kk][tn];
            float4 b1 = *(const float4*)&Bs[kk][tn + 4];
            float av[8] = {a0.x, a0.y, a0.z, a0.w, a1.x, a1.y, a1.z, a1.w};
            float bv[8] = {b0.x, b0.y, b0.z, b0.w, b1.x, b1.y, b1.z, b1.w};
#pragma unroll
            for (int i = 0; i < 8; i++)
#pragma unroll
                for (int j = 0; j < 8; j++)
                    acc[i][j] = fmaf(av[i], bv[j], acc[i][j]);
        }
    }

    const bool isA = (bn < 4);
    float* Cout = isA ? Aout : Mout;
    const float* bias = isA ? tau_b : mem_b;
    const int ncol0 = (isA ? n0 : n0 - 512) + tn;
    float bj[8];
#pragma unroll
    for (int j = 0; j < 8; j++) bj[j] = bias[ncol0 + j];
#pragma unroll
    for (int i = 0; i < 8; i++) {
        size_t off = (size_t)(m0 + tm + i) * 512 + ncol0;
        float4 o0, o1;
        o0.x = acc[i][0] + bj[0]; o0.y = acc[i][1] + bj[1];
        o0.z = acc[i][2] + bj[2]; o0.w = acc[i][3] + bj[3];
        o1.x = acc[i][4] + bj[4]; o1.y = acc[i][5] + bj[5];
        o1.z = acc[i][6] + bj[6]; o1.w = acc[i][7] + bj[7];
        *(float4*)&Cout[off] = o0;
        *(float4*)&Cout[off + 4] = o1;
    }
}

// ---------------------------------------------------------------------------
// Kernel 3: reset sync state every launch (graph-replay safe).
// Slot0 words = {seq=0, tau=1.0} (the t=0 carry); slot1 words = {seq=0, *}.
// Both slots MUST be reset: seq is the readiness signal now.
// ---------------------------------------------------------------------------
__global__ void init_sync(u64* __restrict__ xchg, int* __restrict__ ctr) {
    int idx = blockIdx.x * 256 + threadIdx.x;   // 0 .. 65535
    if (idx < 2 * XWORDS) xchg[idx] = (idx < XWORDS) ? 0x3F800000ull : 0ull;
    if (idx < 16) ctr[idx] = 0;
}

// ---------------------------------------------------------------------------
// Kernel 4: cooperative scan, LDS weights + flag-free single-hop exchange.
//
// Roles assigned DYNAMICALLY by physical XCD (s_getreg HW_REG_XCC_ID, m09):
// block on XCD x with rank r (atomicAdd) gets sg=r&7, bp=x*4+(r>>3).
// All 8 segment-partners of a batch-pair are then co-XCD regardless of the
// (undefined) blockIdx->XCD mapping — round-6 lesson: the 6.5us/step was
// consistent with every sync hop crossing XCDs. 1 block/CU (140KB LDS)
// guarantees exactly 32 blocks/XCD, so roles stay bijective; if XCC_ID
// ever read constant, the mapping degrades to a still-bijective global one.
//
// Exchange: tau published as one atomic 8B word {seq:u32 | tau:f32} —
// readers poll the word itself (readiness+data in ONE hop; no flags, no
// pre-flag vmcnt-drain barrier). Parity double-buffer; induction "writer
// sees partners' step-c pubs => partners consumed c-1" makes reuse safe.
// ---------------------------------------------------------------------------
__global__ __launch_bounds__(512)
__attribute__((amdgpu_waves_per_eu(2, 2)))
void scan_lds(const float* __restrict__ WTh,
              const float* __restrict__ Mm,
              const float* __restrict__ log_thresh,
              float* __restrict__ AmOut,   // A in / spikes out (d_out)
              float* __restrict__ OutTail, // d_out base for tau/v tails
              u64* __restrict__ xchg,
              int* __restrict__ ctr) {
    __shared__ __align__(16) float4 w_lds[8192];       // 128 KB
    __shared__ __align__(16) float tau_s[2][512];      // 4 KB
    __shared__ __align__(16) float part[2][16][64];    // 8 KB
    __shared__ int role_s;

    const int tid = threadIdx.x;

    if (tid == 0) {
        unsigned xcd;
        asm volatile("s_getreg_b32 %0, hwreg(HW_REG_XCC_ID)" : "=s"(xcd));
        xcd &= 7;
        int rank = atomicAdd(&ctr[xcd], 1) & 31;
        role_s = ((rank & 7) << 8) | ((int)xcd * 4 + (rank >> 3));
    }
    __syncthreads();
    const int sg = role_s >> 8;    // channel segment 0..7
    const int bp = role_s & 255;   // batch pair 0..31

    // ---- stage weight slice into LDS (one-time, 128 KB) ----
    {
        const int ch = tid & 63;
        const int kr8 = tid >> 6;          // 0..7
        float* wl = (float*)w_lds;
        for (int i = 0; i < 64; i++) {
            int krow = i * 8 + kr8;
            float val = WTh[krow * 512 + sg * 64 + ch];
            wl[(krow >> 2) * 256 + ch * 4 + (krow & 3)] = val;
        }
    }

    // epilogue identity (tid < 128): batch-in-pair eb, channel ech
    const int eb = tid >> 6;             // 0 or 1 (for tid<128)
    const int ech = tid & 63;
    const int gch = sg * 64 + ech;       // global channel
    float thr = 0.f, v = 0.f, tau_keep = 0.f;
    if (tid < 128) thr = 1.0f / (1.0f + expf(-log_thresh[gch]));
    size_t abase = ((size_t)(bp * 2 + eb) * T_) * D_ + gch;

    // GEMV identity
    const int cp = tid & 31;             // channel pair (cp, cp+32)
    const int ks = tid >> 5;             // k-slice 0..15 (window of 32 k)

    // gather identity (tid < 256): batch-in-pair gb, float4-group ge
    const int gb = (tid >> 7) & 1;
    const int ge = tid & 127;

    __syncthreads();   // weights staged

    for (int c = 1; c <= T_; c++) {
        // prefetch this step's A and M (complete during the poll)
        float a_in = 0.f, m_in = 0.f;
        if (tid < 128) { a_in = AmOut[abase]; m_in = Mm[abase]; }

        // ---- poll-gather: the 8B word carries {seq, tau} — one hop ----
        if (tid < 256) {
            const u64* src = xchg + (size_t)((c - 1) & 1) * XWORDS
                                  + (bp * 2 + gb) * 512 + ge * 4;
            const unsigned tgt = (unsigned)(c - 1);
            u64 v0, v1, v2, v3;
            int guard = 0;
            do {
                v0 = __hip_atomic_load(src + 0, __ATOMIC_RELAXED,
                                       __HIP_MEMORY_SCOPE_AGENT);
                v1 = __hip_atomic_load(src + 1, __ATOMIC_RELAXED,
                                       __HIP_MEMORY_SCOPE_AGENT);
                v2 = __hip_atomic_load(src + 2, __ATOMIC_RELAXED,
                                       __HIP_MEMORY_SCOPE_AGENT);
                v3 = __hip_atomic_load(src + 3, __ATOMIC_RELAXED,
                                       __HIP_MEMORY_SCOPE_AGENT);
            } while ((((unsigned)(v0 >> 32) < tgt) |
                      ((unsigned)(v1 >> 32) < tgt) |
                      ((unsigned)(v2 >> 32) < tgt) |
                      ((unsigned)(v3 >> 32) < tgt)) && ++guard < (1 << 22));
            float4 tv = make_float4(__uint_as_float((unsigned)v0),
                                    __uint_as_float((unsigned)v1),
                                    __uint_as_float((unsigned)v2),
                                    __uint_as_float((unsigned)v3));
            *(float4*)&tau_s[gb][ge * 4] = tv;
        }
        __syncthreads();   // B: tau_s ready

        // ---- GEMV: 2 channels x 2 batches over k-window [ks*32, ks*32+32) ----
        float acc00 = 0.f, acc01 = 0.f, acc10 = 0.f, acc11 = 0.f;
#pragma unroll
        for (int q = 0; q < 8; q++) {
            const int qq = ks * 8 + q;
            float4 wA = w_lds[qq * 64 + cp];
            float4 wB = w_lds[qq * 64 + cp + 32];
            float4 t0 = *(const float4*)&tau_s[0][qq * 4];
            float4 t1 = *(const float4*)&tau_s[1][qq * 4];
            acc00 = fmaf(t0.x, wA.x, acc00); acc00 = fmaf(t0.y, wA.y, acc00);
            acc00 = fmaf(t0.z, wA.z, acc00); acc00 = fmaf(t0.w, wA.w, acc00);
            acc01 = fmaf(t0.x, wB.x, acc01); acc01 = fmaf(t0.y, wB.y, acc01);
            acc01 = fmaf(t0.z, wB.z, acc01); acc01 = fmaf(t0.w, wB.w, acc01);
            acc10 = fmaf(t1.x, wA.x, acc10); acc10 = fmaf(t1.y, wA.y, acc10);
            acc10 = fmaf(t1.z, wA.z, acc10); acc10 = fmaf(t1.w, wA.w, acc10);
            acc11 = fmaf(t1.x, wB.x, acc11); acc11 = fmaf(t1.y, wB.y, acc11);
            acc11 = fmaf(t1.z, wB.z, acc11); acc11 = fmaf(t1.w, wB.w, acc11);
        }
        part[0][ks][cp]      = acc00;
        part[0][ks][cp + 32] = acc01;
        part[1][ks][cp]      = acc10;
        part[1][ks][cp + 32] = acc11;
        __syncthreads();   // C: partials ready

        // ---- epilogue on 128 threads; the store IS the publication ----
        if (tid < 128) {
            float sum = 0.f;
#pragma unroll
            for (int j = 0; j < 16; j++) sum += part[eb][j][ech];
            float pre = sum + a_in;
            float tau = 1.0f / (1.0f + expf(-pre));
            float alpha = expf(-1.0f / (tau + 1e-6f));
            v = alpha * v + (1.0f - alpha) * m_in;
            float s = (v >= thr) ? 1.0f : 0.0f;
            AmOut[abase] = s;            // overwrite A slot with spike
            v = v * (1.0f - s);
            tau_keep = tau;
            u64 pack = ((u64)(unsigned)c << 32) | (u64)__float_as_uint(tau);
            __hip_atomic_store(&xchg[(size_t)(c & 1) * XWORDS
                                     + (bp * 2 + eb) * 512 + gch],
                               pack, __ATOMIC_RELAXED, __HIP_MEMORY_SCOPE_AGENT);
            abase += D_;
        }
        // no barrier D, no flag — next iteration's poll does the waiting
    }

    if (tid < 128) {
        const size_t batch = bp * 2 + eb;
        OutTail[(size_t)BT_ * D_ + batch * D_ + gch] = tau_keep;
        OutTail[(size_t)BT_ * D_ + (size_t)B_ * D_ + batch * D_ + gch] = v;
    }
}

// ---------------------------------------------------------------------------
extern "C" void kernel_launch(void* const* d_in, const int* in_sizes, int n_in,
                              void* d_out, int out_size, void* d_ws, size_t ws_size,
                              hipStream_t stream) {
    (void)in_sizes; (void)n_in; (void)out_size; (void)ws_size;
    const float* x          = (const float*)d_in[0];
    const float* tau_w      = (const float*)d_in[1];
    const float* tau_b      = (const float*)d_in[2];
    const float* mem_w      = (const float*)d_in[3];
    const float* mem_b      = (const float*)d_in[4];
    const float* log_thresh = (const float*)d_in[5];
    float* out = (float*)d_out;

    // workspace layout
    float* Wcat = (float*)d_ws;            // 512*1024 (dead after GEMM)
    float* WTh  = Wcat + 512 * 1024;       // 512*512
    float* Mout = WTh + 512 * 512;         // 131072*512
    // sync state reuses the Wcat region (GEMM finishes before init_sync)
    u64* xchg = (u64*)d_ws;                           // 2*XWORDS*8 = 512 KB
    int* ctr  = (int*)((char*)d_ws + 2 * XWORDS * sizeof(u64));

    float* Aout = out;                     // spikes region doubles as A buffer

    prep_weights<<<2048, 256, 0, stream>>>(tau_w, mem_w, Wcat, WTh);
    gemm_xw<<<dim3(8, 1024), 256, 0, stream>>>(x, Wcat, tau_b, mem_b, Aout, Mout);
    init_sync<<<256, 256, 0, stream>>>(xchg, ctr);

    const float* WThc = WTh;
    const float* Mmc  = Mout;
    const float* ltc  = log_thresh;
    float* outp = out;
    u64* xchgp = xchg;
    int* ctrp = ctr;
    void* args[7] = {(void*)&WThc, (void*)&Mmc, (void*)&ltc,
                     (void*)&Aout, (void*)&outp, (void*)&xchgp, (void*)&ctrp};
    hipLaunchCooperativeKernel((const void*)scan_lds, dim3(256), dim3(512),
                               args, 0, stream);
}

// Round 8
// 5411.411 us; speedup vs baseline: 3.8726x; 1.1904x over previous
//
#include <hip/hip_runtime.h>
#include <math.h>

#define B_ 64
#define T_ 2048
#define D_ 512
#define BT_ (B_ * T_)   // 131072
#define XWORDS (B_ * D_)   // 32768 8-byte words per parity slot: [batch][512]

typedef unsigned long long u64;

// ---------------------------------------------------------------------------
// Kernel 1: weight prep (transpose to k-major for coalesced GEMM/GEMV reads)
// ---------------------------------------------------------------------------
__global__ void prep_weights(const float* __restrict__ tau_w,
                             const float* __restrict__ mem_w,
                             float* __restrict__ Wcat,
                             float* __restrict__ WTh) {
    int idx = blockIdx.x * 256 + threadIdx.x;   // 0 .. 524287
    {
        int k = idx >> 10, j = idx & 1023;
        float v = (j < 512) ? tau_w[j * 1024 + k] : mem_w[(j - 512) * 512 + k];
        Wcat[idx] = v;
    }
    if (idx < 512 * 512) {
        int k = idx >> 9, d = idx & 511;
        WTh[idx] = tau_w[d * 1024 + 512 + k];
    }
}

// ---------------------------------------------------------------------------
// Kernel 2: f32 GEMM  C[131072][1024] = X[131072][512] @ Wcat[512][1024] + bias
// ---------------------------------------------------------------------------
__global__ __launch_bounds__(256, 2)
void gemm_xw(const float* __restrict__ X, const float* __restrict__ Wc,
             const float* __restrict__ tau_b, const float* __restrict__ mem_b,
             float* __restrict__ Aout, float* __restrict__ Mout) {
    __shared__ __align__(16) float As[16][128];  // [k][m]
    __shared__ __align__(16) float Bs[16][128];  // [k][n]
    const int bn = blockIdx.x;          // 0..7
    const int bm = blockIdx.y;          // 0..1023
    const int tid = threadIdx.x;
    const int tm = (tid >> 4) << 3;
    const int tn = (tid & 15) << 3;
    const int m0 = bm * 128, n0 = bn * 128;

    const float4* X4 = (const float4*)X;
    const float4* Wc4 = (const float4*)Wc;

    float acc[8][8];
#pragma unroll
    for (int i = 0; i < 8; i++)
#pragma unroll
        for (int j = 0; j < 8; j++) acc[i][j] = 0.0f;

    const int ar = tid >> 1;              // 0..127 row in tile
    const int ac2 = (tid & 1) * 2;        // float4 col 0 or 2
    const int bkr = tid >> 4;             // 0..15
    const int bc = (tid & 15) * 2;        // float4 col 0..30

    for (int kt = 0; kt < 512; kt += 16) {
        float4 av0 = X4[(m0 + ar) * 128 + (kt >> 2) + ac2];
        float4 av1 = X4[(m0 + ar) * 128 + (kt >> 2) + ac2 + 1];
        float4 bv0 = Wc4[(kt + bkr) * 256 + bn * 32 + bc];
        float4 bv1 = Wc4[(kt + bkr) * 256 + bn * 32 + bc + 1];
        __syncthreads();   // protect previous iteration's reads
        As[ac2 * 4 + 0][ar] = av0.x;
        As[ac2 * 4 + 1][ar] = av0.y;
        As[ac2 * 4 + 2][ar] = av0.z;
        As[ac2 * 4 + 3][ar] = av0.w;
        As[ac2 * 4 + 4][ar] = av1.x;
        As[ac2 * 4 + 5][ar] = av1.y;
        As[ac2 * 4 + 6][ar] = av1.z;
        As[ac2 * 4 + 7][ar] = av1.w;
        *(float4*)&Bs[bkr][bc * 4] = bv0;
        *(float4*)&Bs[bkr][bc * 4 + 4] = bv1;
        __syncthreads();
#pragma unroll
        for (int kk = 0; kk < 16; kk++) {
            float4 a0 = *(const float4*)&As[kk][tm];
            float4 a1 = *(const float4*)&As[kk][tm + 4];
            float4 b0 = *(const float4*)&Bs[kk][tn];
            float4 b1 = *(const float4*)&Bs[kk][tn + 4];
            float av[8] = {a0.x, a0.y, a0.z, a0.w, a1.x, a1.y, a1.z, a1.w};
            float bv[8] = {b0.x, b0.y, b0.z, b0.w, b1.x, b1.y, b1.z, b1.w};
#pragma unroll
            for (int i = 0; i < 8; i++)
#pragma unroll
                for (int j = 0; j < 8; j++)
                    acc[i][j] = fmaf(av[i], bv[j], acc[i][j]);
        }
    }

    const bool isA = (bn < 4);
    float* Cout = isA ? Aout : Mout;
    const float* bias = isA ? tau_b : mem_b;
    const int ncol0 = (isA ? n0 : n0 - 512) + tn;
    float bj[8];
#pragma unroll
    for (int j = 0; j < 8; j++) bj[j] = bias[ncol0 + j];
#pragma unroll
    for (int i = 0; i < 8; i++) {
        size_t off = (size_t)(m0 + tm + i) * 512 + ncol0;
        float4 o0, o1;
        o0.x = acc[i][0] + bj[0]; o0.y = acc[i][1] + bj[1];
        o0.z = acc[i][2] + bj[2]; o0.w = acc[i][3] + bj[3];
        o1.x = acc[i][4] + bj[4]; o1.y = acc[i][5] + bj[5];
        o1.z = acc[i][6] + bj[6]; o1.w = acc[i][7] + bj[7];
        *(float4*)&Cout[off] = o0;
        *(float4*)&Cout[off + 4] = o1;
    }
}

// ---------------------------------------------------------------------------
// Kernel 3: reset sync state every launch (graph-replay safe).
// Slot0 words = {seq=0, tau=1.0} (the t=0 carry); slot1 words = {seq=0, *}.
// ---------------------------------------------------------------------------
__global__ void init_sync(u64* __restrict__ xchg, int* __restrict__ ctr) {
    int idx = blockIdx.x * 256 + threadIdx.x;   // 0 .. 65535
    if (idx < 2 * XWORDS) xchg[idx] = (idx < XWORDS) ? 0x3F800000ull : 0ull;
    if (idx < 16) ctr[idx] = 0;
}

// ---------------------------------------------------------------------------
// Kernel 4: cooperative scan — wave-specialized arrival-order compute.
//
// 256 blocks = (seg sg: 64 channels) x (batch-pair bp), roles assigned by
// physical XCD (s_getreg XCC_ID + atomicAdd rank) so all 8 partners of a
// batch-pair are co-XCD (round-7 win, kept).
//
// Round-8 change: wave w (= exactly 64 lanes) owns k-window [w*64,w*64+64),
// whose tau inputs come from segment w ONLY. Each wave polls just its own
// source segment's 128 words {seq|tau}, drops them in its PRIVATE tau_s
// section, and starts its FMA window immediately — no block barrier between
// gather and compute (per-wave LDS pipe is in-order). Critical path per step
// = visibility + detect + 1/8 GEMV + 1 barrier + epilogue, instead of
// visibility + detect + barrier + full GEMV + barrier + epilogue.
// Self-segment (w==sg) never polls: the epilogue writes its tau directly
// into LDS. FMA grouping and reduce order are BIT-IDENTICAL to round 7
// (16 slots x 32 contiguous k, sequential reduce) => spikes can't flip.
// ---------------------------------------------------------------------------
__global__ __launch_bounds__(512)
__attribute__((amdgpu_waves_per_eu(2, 2)))
void scan_wave(const float* __restrict__ WTh,
               const float* __restrict__ Mm,
               const float* __restrict__ log_thresh,
               float* __restrict__ AmOut,   // A in / spikes out (d_out)
               float* __restrict__ OutTail, // d_out base for tau/v tails
               u64* __restrict__ xchg,
               int* __restrict__ ctr) {
    __shared__ __align__(16) float4 w_lds[8192];       // 128 KB
    __shared__ __align__(16) float tau_s[2][512];      // 4 KB
    __shared__ __align__(16) float part[2][16][64];    // 8 KB
    __shared__ int role_s;

    const int tid = threadIdx.x;

    if (tid == 0) {
        unsigned xcd;
        asm volatile("s_getreg_b32 %0, hwreg(HW_REG_XCC_ID)" : "=s"(xcd));
        xcd &= 7;
        int rank = atomicAdd(&ctr[xcd], 1) & 31;
        role_s = ((rank & 7) << 8) | ((int)xcd * 4 + (rank >> 3));
    }
    __syncthreads();
    const int sg = role_s >> 8;    // channel segment 0..7
    const int bp = role_s & 255;   // batch pair 0..31

    // ---- stage weight slice into LDS (one-time, 128 KB) ----
    {
        const int ch = tid & 63;
        const int kr8 = tid >> 6;          // 0..7
        float* wl = (float*)w_lds;
        for (int i = 0; i < 64; i++) {
            int krow = i * 8 + kr8;
            float val = WTh[krow * 512 + sg * 64 + ch];
            wl[(krow >> 2) * 256 + ch * 4 + (krow & 3)] = val;
        }
    }

    // wave identity: wave ws sources segment ws, k-window [ws*64, ws*64+64)
    const int ws = tid >> 6;             // 0..7 (one full wave each)
    const int lane = tid & 63;
    const int cp = lane & 31;            // channel pair (cp, cp+32)
    const int kh = lane >> 5;            // k-half within window (32 k each)
    const bool self = (ws == sg);

    // epilogue identity (tid < 128)
    const int eb = tid >> 6;             // 0 or 1
    const int ech = tid & 63;
    const int gch = sg * 64 + ech;
    float thr = 0.f, v = 0.f, tau_keep = 0.f;
    if (tid < 128) thr = 1.0f / (1.0f + expf(-log_thresh[gch]));
    size_t abase = ((size_t)(bp * 2 + eb) * T_) * D_ + gch;

    // initial carry for self segment (partners read slot0 init = 1.0)
    if (tid < 128) tau_s[eb][sg * 64 + ech] = 1.0f;
    __syncthreads();   // weights staged + self tau init

    for (int c = 1; c <= T_; c++) {
        // prefetch this step's A and M (consumed in epilogue)
        float a_in = 0.f, m_in = 0.f;
        if (tid < 128) { a_in = AmOut[abase]; m_in = Mm[abase]; }

        // ---- per-wave poll-gather of source segment ws (skip if self) ----
        if (!self) {
            const u64* s0 = xchg + (size_t)((c - 1) & 1) * XWORDS
                                 + (size_t)(bp * 2) * 512 + ws * 64 + lane;
            const u64* s1 = s0 + 512;   // batch 1 of the pair
            const unsigned tgt = (unsigned)(c - 1);
            u64 v0, v1;
            int guard = 0;
            do {
                v0 = __hip_atomic_load(s0, __ATOMIC_RELAXED,
                                       __HIP_MEMORY_SCOPE_AGENT);
                v1 = __hip_atomic_load(s1, __ATOMIC_RELAXED,
                                       __HIP_MEMORY_SCOPE_AGENT);
            } while ((((unsigned)(v0 >> 32) < tgt) |
                      ((unsigned)(v1 >> 32) < tgt)) && ++guard < (1 << 22));
            tau_s[0][ws * 64 + lane] = __uint_as_float((unsigned)v0);
            tau_s[1][ws * 64 + lane] = __uint_as_float((unsigned)v1);
        }
        __builtin_amdgcn_wave_barrier();   // no compiler motion across gather

        // ---- FMA over own 64-k window (2 ch x 2 batches x 32 k) ----
        float acc00 = 0.f, acc01 = 0.f, acc10 = 0.f, acc11 = 0.f;
#pragma unroll
        for (int q = 0; q < 8; q++) {
            const int qq = ws * 16 + kh * 8 + q;
            float4 wA = w_lds[qq * 64 + cp];
            float4 wB = w_lds[qq * 64 + cp + 32];
            float4 t0 = *(const float4*)&tau_s[0][ws * 64 + kh * 32 + q * 4];
            float4 t1 = *(const float4*)&tau_s[1][ws * 64 + kh * 32 + q * 4];
            acc00 = fmaf(t0.x, wA.x, acc00); acc00 = fmaf(t0.y, wA.y, acc00);
            acc00 = fmaf(t0.z, wA.z, acc00); acc00 = fmaf(t0.w, wA.w, acc00);
            acc01 = fmaf(t0.x, wB.x, acc01); acc01 = fmaf(t0.y, wB.y, acc01);
            acc01 = fmaf(t0.z, wB.z, acc01); acc01 = fmaf(t0.w, wB.w, acc01);
            acc10 = fmaf(t1.x, wA.x, acc10); acc10 = fmaf(t1.y, wA.y, acc10);
            acc10 = fmaf(t1.z, wA.z, acc10); acc10 = fmaf(t1.w, wA.w, acc10);
            acc11 = fmaf(t1.x, wB.x, acc11); acc11 = fmaf(t1.y, wB.y, acc11);
            acc11 = fmaf(t1.z, wB.z, acc11); acc11 = fmaf(t1.w, wB.w, acc11);
        }
        const int slot = ws * 2 + kh;      // same k->slot map as round 7
        part[0][slot][cp]      = acc00;
        part[0][slot][cp + 32] = acc01;
        part[1][slot][cp]      = acc10;
        part[1][slot][cp + 32] = acc11;
        __syncthreads();   // A: all 16 partial slots ready

        // ---- epilogue on 128 threads; store IS the publication ----
        if (tid < 128) {
            float sum = 0.f;
#pragma unroll
            for (int j = 0; j < 16; j++) sum += part[eb][j][ech];
            float pre = sum + a_in;
            float tau = 1.0f / (1.0f + expf(-pre));
            float alpha = expf(-1.0f / (tau + 1e-6f));
            v = alpha * v + (1.0f - alpha) * m_in;
            float s = (v >= thr) ? 1.0f : 0.0f;
            AmOut[abase] = s;            // overwrite A slot with spike
            v = v * (1.0f - s);
            tau_keep = tau;
            tau_s[eb][sg * 64 + ech] = tau;   // self-segment LDS shortcut
            u64 pack = ((u64)(unsigned)c << 32) | (u64)__float_as_uint(tau);
            __hip_atomic_store(&xchg[(size_t)(c & 1) * XWORDS
                                     + (bp * 2 + eb) * 512 + gch],
                               pack, __ATOMIC_RELAXED, __HIP_MEMORY_SCOPE_AGENT);
            abase += D_;
        }
        __syncthreads();   // B: part[] free to overwrite, self tau_s visible
    }

    if (tid < 128) {
        const size_t batch = bp * 2 + eb;
        OutTail[(size_t)BT_ * D_ + batch * D_ + gch] = tau_keep;
        OutTail[(size_t)BT_ * D_ + (size_t)B_ * D_ + batch * D_ + gch] = v;
    }
}

// ---------------------------------------------------------------------------
extern "C" void kernel_launch(void* const* d_in, const int* in_sizes, int n_in,
                              void* d_out, int out_size, void* d_ws, size_t ws_size,
                              hipStream_t stream) {
    (void)in_sizes; (void)n_in; (void)out_size; (void)ws_size;
    const float* x          = (const float*)d_in[0];
    const float* tau_w      = (const float*)d_in[1];
    const float* tau_b      = (const float*)d_in[2];
    const float* mem_w      = (const float*)d_in[3];
    const float* mem_b      = (const float*)d_in[4];
    const float* log_thresh = (const float*)d_in[5];
    float* out = (float*)d_out;

    // workspace layout
    float* Wcat = (float*)d_ws;            // 512*1024 (dead after GEMM)
    float* WTh  = Wcat + 512 * 1024;       // 512*512
    float* Mout = WTh + 512 * 512;         // 131072*512
    // sync state reuses the Wcat region (GEMM finishes before init_sync)
    u64* xchg = (u64*)d_ws;                           // 2*XWORDS*8 = 512 KB
    int* ctr  = (int*)((char*)d_ws + 2 * XWORDS * sizeof(u64));

    float* Aout = out;                     // spikes region doubles as A buffer

    prep_weights<<<2048, 256, 0, stream>>>(tau_w, mem_w, Wcat, WTh);
    gemm_xw<<<dim3(8, 1024), 256, 0, stream>>>(x, Wcat, tau_b, mem_b, Aout, Mout);
    init_sync<<<256, 256, 0, stream>>>(xchg, ctr);

    const float* WThc = WTh;
    const float* Mmc  = Mout;
    const float* ltc  = log_thresh;
    float* outp = out;
    u64* xchgp = xchg;
    int* ctrp = ctr;
    void* args[7] = {(void*)&WThc, (void*)&Mmc, (void*)&ltc,
                     (void*)&Aout, (void*)&outp, (void*)&xchgp, (void*)&ctrp};
    hipLaunchCooperativeKernel((const void*)scan_wave, dim3(256), dim3(512),
                               args, 0, stream);
}